// Round 2
// baseline (551.610 us; speedup 1.0000x reference)
//
#include <hip/hip_runtime.h>

#define BT 16384
#define NF 39
#define FD 26000

typedef unsigned short u16;
typedef unsigned int u32;
typedef short bf16x8 __attribute__((ext_vector_type(8)));
typedef float f32x4 __attribute__((ext_vector_type(4)));

__device__ __forceinline__ float bf2f(u16 h) {
  union { u32 u; float f; } v; v.u = ((u32)h) << 16; return v.f;
}
__device__ __forceinline__ u16 f2bf(float f) {
  union { float f; u32 u; } v; v.f = f;
  u32 r = v.u + 0x7fffu + ((v.u >> 16) & 1u);
  return (u16)(r >> 16);
}

// ---------------------------------------------------------------------------
// Kernel A: embedding gather (f32) + gate + per-field 64x64 linear (bf16 MFMA)
// + FM + first-order lin term. One block = 64 batch rows, loops 39 fields.
// ---------------------------------------------------------------------------
__global__ __launch_bounds__(256) void k_embed(
    const int* __restrict__ x, const float* __restrict__ emb,
    const float* __restrict__ lin_table, const float* __restrict__ lin_bias,
    const float* __restrict__ sparse_var, const float* __restrict__ Wt,
    const float* __restrict__ bt, u16* __restrict__ h0, float* __restrict__ base)
{
  __shared__ u16                s_x[64 * NF];     // 4992 B (ids < 26000 fit u16)
  __shared__ float              s_sv[NF * 64];    // 9984 B
  __shared__ float              s_bt[NF * 64];    // 9984 B
  __shared__ __align__(16) u16  s_emb[64 * 72];   // 9216 B (stride 72: 144B rows)
  __shared__ __align__(16) u16  s_wt[64 * 72];    // 9216 B
  __shared__ float              s_S[64 * 65];     // 16640 B
  __shared__ float              s_Q[64];          // 256 B   -> 60288 B total

  const int tid = threadIdx.x;
  const int b0 = blockIdx.x * 64;

  for (int i = tid; i < 64 * NF; i += 256) s_x[i] = (u16)x[b0 * NF + i];
  for (int i = tid; i < NF * 64; i += 256) {
    float v = sparse_var[i];
    float s = 1.0f / (1.0f + __expf(-15.0f * v));
    s_sv[i] = (s > 0.001f) ? s : 0.0f;
    s_bt[i] = bt[i];
  }
  __syncthreads();

  const int wave = tid >> 6, lane = tid & 63;
  const int quad = lane >> 4, c16 = lane & 15;

  float q[4] = {0.f, 0.f, 0.f, 0.f};   // per-lane sum of trans^2, by reg r
  float accS[4][4];                     // [nt][r] running sum_f trans
  #pragma unroll
  for (int nt = 0; nt < 4; ++nt)
    #pragma unroll
    for (int r = 0; r < 4; ++r) accS[nt][r] = 0.f;

  for (int f = 0; f < NF; ++f) {
    // stage Wt[f] (64x64 f32 row-major) -> bf16 LDS
    #pragma unroll
    for (int it = 0; it < 4; ++it) {
      int s = tid + it * 256;
      int row = s >> 4, c4 = (s & 15) * 4;
      float4 w = *(const float4*)&Wt[f * 4096 + row * 64 + c4];
      union { uint2 v; u16 h[4]; } p;
      p.h[0] = f2bf(w.x); p.h[1] = f2bf(w.y);
      p.h[2] = f2bf(w.z); p.h[3] = f2bf(w.w);
      *(uint2*)&s_wt[row * 72 + c4] = p.v;
    }
    // gather + gate embeddings (f32 rows, 256B each) -> bf16 LDS + h0
    #pragma unroll
    for (int it = 0; it < 4; ++it) {
      int s = tid + it * 256;
      int row = s >> 4, c4 = (s & 15) * 4;
      long gi = (long)((int)s_x[row * NF + f] + f * FD);
      float4 e = *(const float4*)&emb[gi * 64 + c4];
      union { uint2 v; u16 h[4]; } p;
      p.h[0] = f2bf(e.x * s_sv[f * 64 + c4 + 0]);
      p.h[1] = f2bf(e.y * s_sv[f * 64 + c4 + 1]);
      p.h[2] = f2bf(e.z * s_sv[f * 64 + c4 + 2]);
      p.h[3] = f2bf(e.w * s_sv[f * 64 + c4 + 3]);
      *(uint2*)&s_emb[row * 72 + c4] = p.v;
      *(uint2*)&h0[(long)(b0 + row) * (NF * 64) + f * 64 + c4] = p.v;
    }
    __syncthreads();

    // trans(64x64) = E @ Wt[f]^T via 16x16x32 MFMA; wave owns 16 rows
    bf16x8 a0 = *(const bf16x8*)&s_emb[(wave * 16 + c16) * 72 + quad * 8];
    bf16x8 a1 = *(const bf16x8*)&s_emb[(wave * 16 + c16) * 72 + 32 + quad * 8];
    #pragma unroll
    for (int nt = 0; nt < 4; ++nt) {
      bf16x8 bb0 = *(const bf16x8*)&s_wt[(nt * 16 + c16) * 72 + quad * 8];
      bf16x8 bb1 = *(const bf16x8*)&s_wt[(nt * 16 + c16) * 72 + 32 + quad * 8];
      f32x4 acc = {0.f, 0.f, 0.f, 0.f};
      acc = __builtin_amdgcn_mfma_f32_16x16x32_bf16(a0, bb0, acc, 0, 0, 0);
      acc = __builtin_amdgcn_mfma_f32_16x16x32_bf16(a1, bb1, acc, 0, 0, 0);
      float btv = s_bt[f * 64 + nt * 16 + c16];
      #pragma unroll
      for (int r = 0; r < 4; ++r) {
        float t = acc[r] + btv;   // trans[row = wave*16+quad*4+r][col = nt*16+c16]
        accS[nt][r] += t;
        q[r] += t * t;
      }
    }
    __syncthreads();   // protect s_emb/s_wt before next field's staging
  }

  // spill S: lane owns (row = wave*16+quad*4+r, col = nt*16+c16)
  #pragma unroll
  for (int nt = 0; nt < 4; ++nt)
    #pragma unroll
    for (int r = 0; r < 4; ++r)
      s_S[(wave * 16 + quad * 4 + r) * 65 + nt * 16 + c16] = accS[nt][r];

  // Q[row]: reduce q[r] across the 16 lanes of each quad
  #pragma unroll
  for (int r = 0; r < 4; ++r) {
    float v = q[r];
    v += __shfl_xor(v, 1, 64);
    v += __shfl_xor(v, 2, 64);
    v += __shfl_xor(v, 4, 64);
    v += __shfl_xor(v, 8, 64);
    if (c16 == 0) s_Q[wave * 16 + quad * 4 + r] = v;
  }
  __syncthreads();

  if (tid < 64) {
    float s2 = 0.f;
    #pragma unroll 8
    for (int e = 0; e < 64; ++e) { float v = s_S[tid * 65 + e]; s2 += v * v; }
    float fmv = 0.5f * (s2 - s_Q[tid]);
    float lv = 0.f;
    #pragma unroll
    for (int f = 0; f < NF; ++f)
      lv += lin_table[(int)s_x[tid * NF + f] + f * FD];
    base[b0 + tid] = lv + lin_bias[0] + fmv;
  }
}

// ---------------------------------------------------------------------------
// MLP GEMM: C(16384x400) = relu((A @ B + b) * BN_INV*g + be), A/Bt/C bf16,
// bias/g/be f32. Bt pre-transposed (400 x K). Tile 128x80x32, XCD swizzle.
// ---------------------------------------------------------------------------
__global__ __launch_bounds__(256) void k_gemm(
    const u16* __restrict__ A, const u16* __restrict__ Bt, int K,
    const float* __restrict__ bias, const float* __restrict__ g,
    const float* __restrict__ be, u16* __restrict__ C)
{
  __shared__ __align__(16) u16 sA[128 * 40];  // stride 40: 80B rows
  __shared__ __align__(16) u16 sB[80 * 40];

  const int tid = threadIdx.x;
  // 640 blocks = 8 xcd * 16 m-groups * 5 n : co-locate one A-panel's 5
  // n-blocks on one XCD for L2 reuse.
  int bid = blockIdx.x;
  int xcd = bid & 7;
  int j = bid >> 3;
  const int m0 = (xcd * 16 + j / 5) * 128;
  const int n0 = (j % 5) * 80;

  const int wave = tid >> 6, lane = tid & 63;
  const int quad = lane >> 4, c16 = lane & 15;

  f32x4 acc[2][5];
  #pragma unroll
  for (int mt = 0; mt < 2; ++mt)
    #pragma unroll
    for (int nt = 0; nt < 5; ++nt) acc[mt][nt] = {0.f, 0.f, 0.f, 0.f};

  for (int k0 = 0; k0 < K; k0 += 32) {
    #pragma unroll
    for (int it = 0; it < 2; ++it) {
      int s = tid + it * 256;
      int row = s >> 2, c = (s & 3) * 8;
      uint4 v = {0u, 0u, 0u, 0u};
      if (k0 + c < K) v = *(const uint4*)&A[(long)(m0 + row) * K + k0 + c];
      *(uint4*)&sA[row * 40 + c] = v;
    }
    for (int s = tid; s < 320; s += 256) {
      int row = s >> 2, c = (s & 3) * 8;
      uint4 v = {0u, 0u, 0u, 0u};
      if (k0 + c < K) v = *(const uint4*)&Bt[(long)(n0 + row) * K + k0 + c];
      *(uint4*)&sB[row * 40 + c] = v;
    }
    __syncthreads();

    bf16x8 a0 = *(const bf16x8*)&sA[(wave * 32 + c16) * 40 + quad * 8];
    bf16x8 a1 = *(const bf16x8*)&sA[(wave * 32 + 16 + c16) * 40 + quad * 8];
    #pragma unroll
    for (int nt = 0; nt < 5; ++nt) {
      bf16x8 b = *(const bf16x8*)&sB[(nt * 16 + c16) * 40 + quad * 8];
      acc[0][nt] = __builtin_amdgcn_mfma_f32_16x16x32_bf16(a0, b, acc[0][nt], 0, 0, 0);
      acc[1][nt] = __builtin_amdgcn_mfma_f32_16x16x32_bf16(a1, b, acc[1][nt], 0, 0, 0);
    }
    __syncthreads();
  }

  const float BN_INV = 0.9999950000374997f;
  #pragma unroll
  for (int nt = 0; nt < 5; ++nt) {
    int col = n0 + nt * 16 + c16;
    float bb = bias[col];
    float sc = BN_INV * g[col];
    float bv = be[col];
    #pragma unroll
    for (int mt = 0; mt < 2; ++mt) {
      #pragma unroll
      for (int r = 0; r < 4; ++r) {
        int row = m0 + wave * 32 + mt * 16 + quad * 4 + r;
        float y = (acc[mt][nt][r] + bb) * sc + bv;
        y = fmaxf(y, 0.f);
        C[(long)row * 400 + col] = f2bf(y);
      }
    }
  }
}

// ---------------------------------------------------------------------------
// Transpose + cast: f32 (R x C) -> bf16 (C x R), 32x32 tiles, bounds-checked.
// ---------------------------------------------------------------------------
__global__ __launch_bounds__(256) void k_transpose(
    const float* __restrict__ in, u16* __restrict__ out, int R, int C)
{
  __shared__ u16 t[32][33];
  int c0 = blockIdx.x * 32, r0 = blockIdx.y * 32;
  int tx = threadIdx.x & 31, ty = threadIdx.x >> 5;
  for (int i = ty; i < 32; i += 8) {
    int r = r0 + i, c = c0 + tx;
    t[i][tx] = (r < R && c < C) ? f2bf(in[(long)r * C + c]) : (u16)0;
  }
  __syncthreads();
  for (int i = ty; i < 32; i += 8) {
    int c = c0 + i, r = r0 + tx;
    if (c < C && r < R) out[(long)c * R + r] = t[tx][i];
  }
}

// ---------------------------------------------------------------------------
// Final: out[b] = sigmoid(base[b] + h3[b,:] . Wout + bout). One wave per row.
// ---------------------------------------------------------------------------
__global__ __launch_bounds__(256) void k_final(
    const u16* __restrict__ h3, const float* __restrict__ Wout,
    const float* __restrict__ bout, const float* __restrict__ base,
    float* __restrict__ out)
{
  int wave = threadIdx.x >> 6, lane = threadIdx.x & 63;
  int b = blockIdx.x * 4 + wave;
  float s = 0.f;
  for (int jj = lane; jj < 400; jj += 64)
    s += bf2f(h3[(long)b * 400 + jj]) * Wout[jj];
  #pragma unroll
  for (int m = 32; m >= 1; m >>= 1) s += __shfl_xor(s, m, 64);
  if (lane == 0) {
    float z = s + base[b] + bout[0];
    out[b] = 1.0f / (1.0f + __expf(-z));
  }
}

extern "C" void kernel_launch(void* const* d_in, const int* in_sizes, int n_in,
                              void* d_out, int out_size, void* d_ws, size_t ws_size,
                              hipStream_t stream)
{
  const int*   x         = (const int*)d_in[0];
  const float* emb       = (const float*)d_in[1];
  const float* lin_table = (const float*)d_in[2];
  const float* lin_bias  = (const float*)d_in[3];
  const float* svar      = (const float*)d_in[4];
  const float* Wt        = (const float*)d_in[5];
  const float* bt        = (const float*)d_in[6];
  const float* W1  = (const float*)d_in[7];
  const float* b1  = (const float*)d_in[8];
  const float* g1  = (const float*)d_in[9];
  const float* be1 = (const float*)d_in[10];
  const float* W2  = (const float*)d_in[11];
  const float* b2  = (const float*)d_in[12];
  const float* g2  = (const float*)d_in[13];
  const float* be2 = (const float*)d_in[14];
  const float* W3  = (const float*)d_in[15];
  const float* b3  = (const float*)d_in[16];
  const float* g3  = (const float*)d_in[17];
  const float* be3 = (const float*)d_in[18];
  const float* Wo  = (const float*)d_in[19];
  const float* bo  = (const float*)d_in[20];

  char* ws = (char*)d_ws;
  size_t off = 0;
  u16* h0 = (u16*)(ws + off);   off += (size_t)BT * (NF * 64) * 2;  // 81.8 MB
  u16* h1 = (u16*)(ws + off);   off += (size_t)BT * 400 * 2;        // 13.1 MB
  u16* h2 = (u16*)(ws + off);   off += (size_t)BT * 400 * 2;        // 13.1 MB
  float* base = (float*)(ws + off); off += (size_t)BT * 4;
  u16* W1T = (u16*)(ws + off);  off += (size_t)2496 * 400 * 2;
  u16* W2T = (u16*)(ws + off);  off += (size_t)400 * 400 * 2;
  u16* W3T = (u16*)(ws + off);  off += (size_t)400 * 400 * 2;
  (void)ws_size; (void)in_sizes; (void)n_in; (void)out_size;

  k_transpose<<<dim3(13, 78), 256, 0, stream>>>(W1, W1T, 2496, 400);
  k_transpose<<<dim3(13, 13), 256, 0, stream>>>(W2, W2T, 400, 400);
  k_transpose<<<dim3(13, 13), 256, 0, stream>>>(W3, W3T, 400, 400);
  k_embed<<<256, 256, 0, stream>>>(x, emb, lin_table, lin_bias, svar, Wt, bt,
                                   h0, base);
  k_gemm<<<640, 256, 0, stream>>>(h0, W1T, 2496, b1, g1, be1, h1);
  k_gemm<<<640, 256, 0, stream>>>(h1, W2T, 400, b2, g2, be2, h2);
  k_gemm<<<640, 256, 0, stream>>>(h2, W3T, 400, b3, g3, be3, h1);  // h3 -> h1
  k_final<<<4096, 256, 0, stream>>>(h1, Wo, bo, base, (float*)d_out);
}

// Round 3
// 479.967 us; speedup vs baseline: 1.1493x; 1.1493x over previous
//
#include <hip/hip_runtime.h>

#define BT 16384
#define NF 39
#define FD 26000

typedef unsigned short u16;
typedef unsigned int u32;
typedef short bf16x8 __attribute__((ext_vector_type(8)));
typedef float f32x4 __attribute__((ext_vector_type(4)));

__device__ __forceinline__ float bf2f(u16 h) {
  union { u32 u; float f; } v; v.u = ((u32)h) << 16; return v.f;
}
__device__ __forceinline__ u16 f2bf(float f) {
  union { float f; u32 u; } v; v.f = f;
  u32 r = v.u + 0x7fffu + ((v.u >> 16) & 1u);
  return (u16)(r >> 16);
}

// async global->LDS, 16B per lane; LDS dest is wave-uniform base + lane*16.
__device__ __forceinline__ void gld16(const u16* g, u16* l) {
  __builtin_amdgcn_global_load_lds(
      (const __attribute__((address_space(1))) void*)g,
      (__attribute__((address_space(3))) void*)l, 16, 0, 0);
}

// ---------------------------------------------------------------------------
// Kernel A: embedding gather + gate + per-field 64x64 linear (MFMA) + FM +
// first-order term. 512 blocks x 32 batch rows (2 blocks/CU for latency hiding).
// ---------------------------------------------------------------------------
__global__ __launch_bounds__(256) void k_embed(
    const int* __restrict__ x, const float* __restrict__ emb,
    const float* __restrict__ lin_table, const float* __restrict__ lin_bias,
    const float* __restrict__ sparse_var, const float* __restrict__ Wt,
    const float* __restrict__ bt, u16* __restrict__ h0, float* __restrict__ base)
{
  __shared__ u16                s_x[32 * NF];     // 2496 B
  __shared__ float              s_sv[NF * 64];    // 9984 B
  __shared__ float              s_bt[NF * 64];    // 9984 B
  __shared__ __align__(16) u16  s_emb[32 * 72];   // 4608 B (stride 72 breaks conflicts)
  __shared__ __align__(16) u16  s_wt[64 * 72];    // 9216 B
  __shared__ float              s_S[32 * 65];     // 8320 B
  __shared__ float              s_Qp[64];         // 256 B
  __shared__ float              s_lin[32];        // 128 B  -> ~45 KB total

  const int tid = threadIdx.x;
  const int b0 = blockIdx.x * 32;

  for (int i = tid; i < 32 * NF; i += 256) s_x[i] = (u16)x[b0 * NF + i];
  for (int i = tid; i < NF * 64; i += 256) {
    float v = sparse_var[i];
    float s = 1.0f / (1.0f + __expf(-15.0f * v));
    s_sv[i] = (s > 0.001f) ? s : 0.0f;
    s_bt[i] = bt[i];
  }
  __syncthreads();

  const int wave = tid >> 6, lane = tid & 63;
  const int quad = lane >> 4, c16 = lane & 15;
  const int mt = wave & 1, nh = wave >> 1;   // wave -> (m-tile, n-half)

  float q[4] = {0.f, 0.f, 0.f, 0.f};
  float accS[2][4];
  #pragma unroll
  for (int j = 0; j < 2; ++j)
    #pragma unroll
    for (int r = 0; r < 4; ++r) accS[j][r] = 0.f;

  // staging indices: 8 threads per row, 8 elems (16B bf16) per thread
  const int g_row = tid >> 3, g_c8 = (tid & 7) * 8;

  for (int f = 0; f < NF; ++f) {
    // Wt[f] (64x64 f32) -> bf16 LDS (2 passes of 32 rows)
    #pragma unroll
    for (int it = 0; it < 2; ++it) {
      int row = g_row + it * 32;
      float4 w0 = *(const float4*)&Wt[f * 4096 + row * 64 + g_c8];
      float4 w1 = *(const float4*)&Wt[f * 4096 + row * 64 + g_c8 + 4];
      union { uint4 v; u16 h[8]; } p;
      p.h[0] = f2bf(w0.x); p.h[1] = f2bf(w0.y); p.h[2] = f2bf(w0.z); p.h[3] = f2bf(w0.w);
      p.h[4] = f2bf(w1.x); p.h[5] = f2bf(w1.y); p.h[6] = f2bf(w1.z); p.h[7] = f2bf(w1.w);
      *(uint4*)&s_wt[row * 72 + g_c8] = p.v;
    }
    // gather + gate 32 embedding rows (256B f32 each) -> bf16 LDS + h0
    {
      long gi = (long)((int)s_x[g_row * NF + f] + f * FD);
      float4 e0 = *(const float4*)&emb[gi * 64 + g_c8];
      float4 e1 = *(const float4*)&emb[gi * 64 + g_c8 + 4];
      union { uint4 v; u16 h[8]; } p;
      p.h[0] = f2bf(e0.x * s_sv[f * 64 + g_c8 + 0]);
      p.h[1] = f2bf(e0.y * s_sv[f * 64 + g_c8 + 1]);
      p.h[2] = f2bf(e0.z * s_sv[f * 64 + g_c8 + 2]);
      p.h[3] = f2bf(e0.w * s_sv[f * 64 + g_c8 + 3]);
      p.h[4] = f2bf(e1.x * s_sv[f * 64 + g_c8 + 4]);
      p.h[5] = f2bf(e1.y * s_sv[f * 64 + g_c8 + 5]);
      p.h[6] = f2bf(e1.z * s_sv[f * 64 + g_c8 + 6]);
      p.h[7] = f2bf(e1.w * s_sv[f * 64 + g_c8 + 7]);
      *(uint4*)&s_emb[g_row * 72 + g_c8] = p.v;
      *(uint4*)&h0[(long)(b0 + g_row) * 2496 + f * 64 + g_c8] = p.v;
    }
    __syncthreads();

    // trans(32x64) = E @ Wt[f]^T ; wave: m-tile mt, n-tiles {nh*2, nh*2+1}
    bf16x8 a0 = *(const bf16x8*)&s_emb[(mt * 16 + c16) * 72 + quad * 8];
    bf16x8 a1 = *(const bf16x8*)&s_emb[(mt * 16 + c16) * 72 + 32 + quad * 8];
    #pragma unroll
    for (int j = 0; j < 2; ++j) {
      int nt = nh * 2 + j;
      bf16x8 bb0 = *(const bf16x8*)&s_wt[(nt * 16 + c16) * 72 + quad * 8];
      bf16x8 bb1 = *(const bf16x8*)&s_wt[(nt * 16 + c16) * 72 + 32 + quad * 8];
      f32x4 acc = {0.f, 0.f, 0.f, 0.f};
      acc = __builtin_amdgcn_mfma_f32_16x16x32_bf16(a0, bb0, acc, 0, 0, 0);
      acc = __builtin_amdgcn_mfma_f32_16x16x32_bf16(a1, bb1, acc, 0, 0, 0);
      float btv = s_bt[f * 64 + nt * 16 + c16];
      #pragma unroll
      for (int r = 0; r < 4; ++r) {
        float t = acc[r] + btv;
        accS[j][r] += t;
        q[r] += t * t;
      }
    }
    __syncthreads();
  }

  // spill S: row = mt*16+quad*4+r, col = nt*16+c16
  #pragma unroll
  for (int j = 0; j < 2; ++j)
    #pragma unroll
    for (int r = 0; r < 4; ++r)
      s_S[(mt * 16 + quad * 4 + r) * 65 + (nh * 2 + j) * 16 + c16] = accS[j][r];

  // Q partials: reduce q[r] over the 16 lanes of each quad -> col-half sums
  #pragma unroll
  for (int r = 0; r < 4; ++r) {
    float v = q[r];
    v += __shfl_xor(v, 1, 64);
    v += __shfl_xor(v, 2, 64);
    v += __shfl_xor(v, 4, 64);
    v += __shfl_xor(v, 8, 64);
    if (c16 == 0) s_Qp[nh * 32 + mt * 16 + quad * 4 + r] = v;
  }

  // first-order term: 8 threads per row, fields strided by 8, shfl-reduce
  {
    int row = tid >> 3, fi = tid & 7;
    float lv = 0.f;
    for (int f = fi; f < NF; f += 8)
      lv += lin_table[(int)s_x[row * NF + f] + f * FD];
    lv += __shfl_xor(lv, 1, 64);
    lv += __shfl_xor(lv, 2, 64);
    lv += __shfl_xor(lv, 4, 64);
    if (fi == 0) s_lin[row] = lv;
  }
  __syncthreads();

  if (tid < 32) {
    float s2 = 0.f;
    #pragma unroll 8
    for (int e = 0; e < 64; ++e) { float v = s_S[tid * 65 + e]; s2 += v * v; }
    float fmv = 0.5f * (s2 - (s_Qp[tid] + s_Qp[32 + tid]));
    base[b0 + tid] = s_lin[tid] + lin_bias[0] + fmv;
  }
}

// ---------------------------------------------------------------------------
// MLP GEMM, m97-style: global_load_lds(16B) staging, XOR-swizzled unpadded
// LDS, tile 128x80xBK64. C = relu((A@B + b)*BN_INV*g + be). K must be kit*64
// (buffers zero-padded to 448 for the 400-dim layers).
// ---------------------------------------------------------------------------
__global__ __launch_bounds__(256) void k_gemm(
    const u16* __restrict__ A, int lda, const u16* __restrict__ Bt, int ldb,
    int kit, const float* __restrict__ bias, const float* __restrict__ g,
    const float* __restrict__ be, u16* __restrict__ C, int ldc)
{
  __shared__ __align__(16) u16 sA[128 * 64];  // 16 KB, 128B rows, chunk-swizzled
  __shared__ __align__(16) u16 sB[80 * 64];   // 10 KB

  const int tid = threadIdx.x;
  // 640 blocks = 8 xcd * 16 m * 5 n : co-locate an A-panel's 5 n-blocks per XCD
  int bid = blockIdx.x;
  int xcd = bid & 7;
  int j = bid >> 3;
  const int m0 = (xcd * 16 + j / 5) * 128;
  const int n0 = (j % 5) * 80;

  const int wave = tid >> 6, lane = tid & 63;
  const int quad = lane >> 4, c16 = lane & 15;

  // staging: lane covers (row = grp*8 + lane>>3, phys chunk = lane&7);
  // fetch logical chunk (lane&7)^(row&7) so reads spread banks evenly.
  const int srow = lane >> 3;
  const int sclog = (lane & 7) ^ (srow & 7);
  const u16* gA = A + (long)m0 * lda + sclog * 8;
  const u16* gB = Bt + (long)n0 * ldb + sclog * 8;

  f32x4 acc[2][5];
  #pragma unroll
  for (int mtt = 0; mtt < 2; ++mtt)
    #pragma unroll
    for (int nt = 0; nt < 5; ++nt) acc[mtt][nt] = {0.f, 0.f, 0.f, 0.f};

  for (int kk = 0; kk < kit; ++kk) {
    const int k0 = kk * 64;
    #pragma unroll
    for (int it = 0; it < 4; ++it) {           // A: wave stages its own 32 rows
      int s = wave * 4 + it;
      gld16(gA + (long)(s * 8 + srow) * lda + k0, &sA[s * 512]);
    }
    gld16(gB + (long)(wave * 8 + srow) * ldb + k0, &sB[wave * 512]);
    gld16(gB + (long)((wave + 4) * 8 + srow) * ldb + k0, &sB[(wave + 4) * 512]);
    if (wave < 2)
      gld16(gB + (long)((wave + 8) * 8 + srow) * ldb + k0, &sB[(wave + 8) * 512]);
    __syncthreads();

    #pragma unroll
    for (int ks = 0; ks < 2; ++ks) {
      const int co = ((ks * 4 + quad) ^ (c16 & 7)) * 8;   // swizzled chunk offset
      bf16x8 a0 = *(const bf16x8*)&sA[(wave * 32 + c16) * 64 + co];
      bf16x8 a1 = *(const bf16x8*)&sA[(wave * 32 + 16 + c16) * 64 + co];
      #pragma unroll
      for (int nt = 0; nt < 5; ++nt) {
        bf16x8 b = *(const bf16x8*)&sB[(nt * 16 + c16) * 64 + co];
        acc[0][nt] = __builtin_amdgcn_mfma_f32_16x16x32_bf16(a0, b, acc[0][nt], 0, 0, 0);
        acc[1][nt] = __builtin_amdgcn_mfma_f32_16x16x32_bf16(a1, b, acc[1][nt], 0, 0, 0);
      }
    }
    __syncthreads();
  }

  const float BN_INV = 0.9999950000374997f;
  #pragma unroll
  for (int nt = 0; nt < 5; ++nt) {
    int col = n0 + nt * 16 + c16;
    float bb = bias[col];
    float sc = BN_INV * g[col];
    float bv = be[col];
    #pragma unroll
    for (int mtt = 0; mtt < 2; ++mtt) {
      #pragma unroll
      for (int r = 0; r < 4; ++r) {
        int row = m0 + wave * 32 + mtt * 16 + quad * 4 + r;
        float y = (acc[mtt][nt][r] + bb) * sc + bv;
        y = fmaxf(y, 0.f);
        C[(long)row * ldc + col] = f2bf(y);
      }
    }
  }
  // zero the K-pad columns (400..ldc) so the next layer's 64-wide k-loop is exact
  if (ldc > 400 && n0 == 320) {
    int npad = ldc - 400;
    for (int s = tid; s < 128 * npad; s += 256) {
      int rr = s / npad, cc = s % npad;
      C[(long)(m0 + rr) * ldc + 400 + cc] = 0;
    }
  }
}

// ---------------------------------------------------------------------------
// All three weight transposes (f32 RxC -> bf16 CxRpad, zero-padded) in one launch.
// ---------------------------------------------------------------------------
__global__ __launch_bounds__(256) void k_transpose3(
    const float* __restrict__ W1, u16* __restrict__ W1T,
    const float* __restrict__ W2, u16* __restrict__ W2T,
    const float* __restrict__ W3, u16* __restrict__ W3T)
{
  int z = blockIdx.z;
  const float* in = (z == 0) ? W1 : (z == 1) ? W2 : W3;
  u16* out = (z == 0) ? W1T : (z == 1) ? W2T : W3T;
  int R = (z == 0) ? 2496 : 400;
  int Rpad = (z == 0) ? 2496 : 448;
  const int C = 400;
  int r0 = blockIdx.y * 32, c0 = blockIdx.x * 32;
  if (r0 >= Rpad) return;
  __shared__ u16 t[32][33];
  int tx = threadIdx.x & 31, ty = threadIdx.x >> 5;
  for (int i = ty; i < 32; i += 8) {
    int r = r0 + i, c = c0 + tx;
    t[i][tx] = (r < R && c < C) ? f2bf(in[(long)r * C + c]) : (u16)0;
  }
  __syncthreads();
  for (int i = ty; i < 32; i += 8) {
    int c = c0 + i, r = r0 + tx;
    if (c < C && r < Rpad) out[(long)c * Rpad + r] = t[tx][i];
  }
}

// ---------------------------------------------------------------------------
// Final: out[b] = sigmoid(base[b] + h3[b,:].Wout + bout). One wave per row.
// ---------------------------------------------------------------------------
__global__ __launch_bounds__(256) void k_final(
    const u16* __restrict__ h3, const float* __restrict__ Wout,
    const float* __restrict__ bout, const float* __restrict__ base,
    float* __restrict__ out)
{
  int wave = threadIdx.x >> 6, lane = threadIdx.x & 63;
  int b = blockIdx.x * 4 + wave;
  float s = 0.f;
  for (int jj = lane; jj < 400; jj += 64)
    s += bf2f(h3[(long)b * 448 + jj]) * Wout[jj];
  #pragma unroll
  for (int m = 32; m >= 1; m >>= 1) s += __shfl_xor(s, m, 64);
  if (lane == 0) {
    float z = s + base[b] + bout[0];
    out[b] = 1.0f / (1.0f + __expf(-z));
  }
}

extern "C" void kernel_launch(void* const* d_in, const int* in_sizes, int n_in,
                              void* d_out, int out_size, void* d_ws, size_t ws_size,
                              hipStream_t stream)
{
  const int*   x         = (const int*)d_in[0];
  const float* emb       = (const float*)d_in[1];
  const float* lin_table = (const float*)d_in[2];
  const float* lin_bias  = (const float*)d_in[3];
  const float* svar      = (const float*)d_in[4];
  const float* Wt        = (const float*)d_in[5];
  const float* bt        = (const float*)d_in[6];
  const float* W1  = (const float*)d_in[7];
  const float* b1  = (const float*)d_in[8];
  const float* g1  = (const float*)d_in[9];
  const float* be1 = (const float*)d_in[10];
  const float* W2  = (const float*)d_in[11];
  const float* b2  = (const float*)d_in[12];
  const float* g2  = (const float*)d_in[13];
  const float* be2 = (const float*)d_in[14];
  const float* W3  = (const float*)d_in[15];
  const float* b3  = (const float*)d_in[16];
  const float* g3  = (const float*)d_in[17];
  const float* be3 = (const float*)d_in[18];
  const float* Wo  = (const float*)d_in[19];
  const float* bo  = (const float*)d_in[20];

  char* ws = (char*)d_ws;
  size_t off = 0;
  u16* h0 = (u16*)(ws + off);   off += (size_t)BT * 2496 * 2;   // 81.8 MB
  u16* h1 = (u16*)(ws + off);   off += (size_t)BT * 448 * 2;    // 14.7 MB
  u16* h2 = (u16*)(ws + off);   off += (size_t)BT * 448 * 2;
  u16* h3 = (u16*)(ws + off);   off += (size_t)BT * 448 * 2;
  float* base = (float*)(ws + off); off += (size_t)BT * 4;
  u16* W1T = (u16*)(ws + off);  off += (size_t)400 * 2496 * 2;
  u16* W2T = (u16*)(ws + off);  off += (size_t)400 * 448 * 2;
  u16* W3T = (u16*)(ws + off);  off += (size_t)400 * 448 * 2;
  (void)ws_size; (void)in_sizes; (void)n_in; (void)out_size;

  k_transpose3<<<dim3(13, 78, 3), 256, 0, stream>>>(W1, W1T, W2, W2T, W3, W3T);
  k_embed<<<512, 256, 0, stream>>>(x, emb, lin_table, lin_bias, svar, Wt, bt,
                                   h0, base);
  k_gemm<<<640, 256, 0, stream>>>(h0, 2496, W1T, 2496, 39, b1, g1, be1, h1, 448);
  k_gemm<<<640, 256, 0, stream>>>(h1, 448, W2T, 448, 7, b2, g2, be2, h2, 448);
  k_gemm<<<640, 256, 0, stream>>>(h2, 448, W3T, 448, 7, b3, g3, be3, h3, 448);
  k_final<<<4096, 256, 0, stream>>>(h3, Wo, bo, base, (float*)d_out);
}